// Round 17
// baseline (321.020 us; speedup 1.0000x reference)
//
#include <hip/hip_runtime.h>
#include <hip/hip_bf16.h>
#include <cstdint>

// ---------------------------------------------------------------------------
// GCN 3-layer forward, bf16 pipeline + MFMA GEMM + fp8 gather operand.
// R17: tier-2 cleanup (gather declared at floor: R15/R16 flat at 51us).
//      (1) pairBuf packed to ONE u32/edge (src:18b | dstLocal:9b) -> halves
//          scatter write + fine read + scatter LDS.
//      (2) bucket-offset scan folded into b_fine (per-block LDS scan of 196
//          counts) -> b_bscan2 launch removed.
//      (3) wpack folded into k_init (grid 26).
//      (4) last-layer gather fuses mean-pool via LDS partials + coalesced
//          per-block partial rows (3.2MB) + k_pred reduce; skips houtb write.
//          (Block-local LDS atomics, NOT R6's 3.2M global atomics.)
// ---------------------------------------------------------------------------

typedef unsigned short u16;
typedef unsigned int u32;
typedef unsigned char u8;
typedef __attribute__((ext_vector_type(8))) short short8v;
typedef __attribute__((ext_vector_type(4))) float f32x4;
typedef __attribute__((ext_vector_type(2))) float f32x2;

#define NBMAX 256
#define BKSH  9
#define SCH   2048
#define CAP   12288   // padded pair slots per bucket

__device__ inline u16 f2bf(float f) {
  u32 u = __float_as_uint(f);
  u += 0x7fff + ((u >> 16) & 1);  // RNE
  return (u16)(u >> 16);
}
__device__ inline float bflo(u32 u) { return __uint_as_float(u << 16); }
__device__ inline float bfhi(u32 u) { return __uint_as_float(u & 0xffff0000u); }

// --- init: blk0 detect edge dtype, blk1 zero cursors/pooled, blk2-25 wpack --
__global__ __launch_bounds__(256) void k_init(const int* __restrict__ ei,
                                              int* __restrict__ mode,
                                              int* __restrict__ bucketCur,
                                              float* __restrict__ pooled,
                                              const float* __restrict__ W0,
                                              const float* __restrict__ W1,
                                              const float* __restrict__ W2,
                                              u16* __restrict__ wp,
                                              int e, int nb) {
  int bid = blockIdx.x;
  if (bid == 0) {
    __shared__ int any;
    if (threadIdx.x == 0) any = 0;
    __syncthreads();
    int lim = min(e, 2048);
    int local = 0;
    for (int i = threadIdx.x; i < lim; i += blockDim.x)
      local |= (ei[2 * i + 1] != 0);
    if (local) atomicOr(&any, 1);
    __syncthreads();
    if (threadIdx.x == 0) mode[0] = (any == 0) ? 1 : 0;
  } else if (bid == 1) {
    int i = threadIdx.x;
    if (i < nb) bucketCur[i] = 0;
    if (i < 128) pooled[i] = 0.0f;
  } else {
    int f = (bid - 2) * 256 + threadIdx.x;   // 0..6143
    int wsel = f >> 11;
    int li = f & 2047;
    const float* W = (wsel == 0) ? W0 : (wsel == 1) ? W1 : W2;
    u16* dst = wp + (size_t)wsel * 2048 * 8;
    int ct = li >> 8, kc = (li >> 6) & 3, lane = li & 63;
    int g = lane >> 4, c = lane & 15;
    u32 o[4];
#pragma unroll
    for (int q = 0; q < 4; ++q) {
      int k = kc * 32 + g * 8 + q * 2;
      u16 e0 = f2bf(W[(size_t)k * 128 + ct * 16 + c]);
      u16 e1 = f2bf(W[(size_t)(k + 1) * 128 + ct * 16 + c]);
      o[q] = (u32)e0 | ((u32)e1 << 16);
    }
    uint4 v; v.x = o[0]; v.y = o[1]; v.z = o[2]; v.w = o[3];
    *reinterpret_cast<uint4*>(dst + (size_t)li * 8) = v;
  }
}

// --- scatter packed edges (src:18b | dstLocal:9b) into padded buckets -------
__global__ __launch_bounds__(256) void b_scatter(const int* __restrict__ ei,
                                                 const int* __restrict__ mode,
                                                 int* __restrict__ bucketCur,
                                                 u32* __restrict__ pairBuf,
                                                 int e, int nb) {
  __shared__ int cnt[NBMAX];
  __shared__ int pre[NBMAX];
  __shared__ int base[NBMAX];
  __shared__ u32 stage[SCH];
  const int t = threadIdx.x;
  const int chunk0 = blockIdx.x * SCH;
  const int nloc = min(SCH, e - chunk0);
  const int m = mode[0];

  cnt[t] = 0;
  __syncthreads();

  u32 myP[SCH / 256];
  int myB[SCH / 256], mySlot[SCH / 256];
#pragma unroll
  for (int j = 0; j < SCH / 256; ++j) {
    int li = j * 256 + t;
    myB[j] = -1;
    if (li < nloc) {
      int i = chunk0 + li;
      long long di = (long long)e + i;
      int s = m ? ei[2 * (long long)i] : ei[i];
      int d = m ? ei[2 * di] : ei[di];
      int b = d >> BKSH;
      myP[j] = (u32)s | ((u32)(d & ((1 << BKSH) - 1)) << 18);
      myB[j] = b;
      mySlot[j] = atomicAdd(&cnt[b], 1);
    }
  }
  __syncthreads();

  int c0 = cnt[t];
  pre[t] = c0;
  __syncthreads();
  for (int d = 1; d < NBMAX; d <<= 1) {
    int v = (t >= d) ? pre[t - d] : 0;
    __syncthreads();
    pre[t] += v;
    __syncthreads();
  }
  int myPre = pre[t] - c0;
  if (t < nb && c0 > 0) base[t] = atomicAdd(&bucketCur[t], c0);  // bucket-rel
  __syncthreads();
  cnt[t] = myPre;
  __syncthreads();

#pragma unroll
  for (int j = 0; j < SCH / 256; ++j) {
    if (myB[j] >= 0)
      stage[cnt[myB[j]] + mySlot[j]] = myP[j];
  }
  __syncthreads();

  int wave = t >> 6, lane = t & 63;
  for (int b = wave; b < nb; b += 4) {
    int cb = pre[b] - cnt[b];
    if (cb <= 0) continue;
    int lo = cnt[b];
    int gb = base[b];
    int room = CAP - gb;
    int allowed = (room > 0) ? min(cb, room) : 0;  // overflow guard (impossible)
    size_t dst = (size_t)b * CAP + gb;
    for (int j = lane; j < allowed; j += 64)
      pairBuf[dst + j] = stage[lo + j];
  }
}

// --- per-bucket fine CSR from packed padded pairs; own bucket-offset scan ---
__global__ __launch_bounds__(512) void b_fine(const u32* __restrict__ pairBuf,
                                              const int* __restrict__ bucketCur,
                                              int* __restrict__ offs,
                                              float* __restrict__ dis,
                                              int* __restrict__ csr,
                                              int n, int e, int nb) {
  const int b = blockIdx.x;
  const int d0 = b << BKSH;
  const size_t pb = (size_t)b * CAP;
  const int cnt = bucketCur[b];
  __shared__ int bc[NBMAX];
  __shared__ int arr[1 << BKSH];
  __shared__ int cur[1 << BKSH];
  const int t = threadIdx.x;

  // exclusive-scan all bucket counts to find this bucket's global csr base
  if (t < NBMAX) bc[t] = (t < nb) ? bucketCur[t] : 0;
  __syncthreads();
  for (int d = 1; d < NBMAX; d <<= 1) {
    int v = (t < NBMAX && t >= d) ? bc[t - d] : 0;
    __syncthreads();
    if (t < NBMAX) bc[t] += v;
    __syncthreads();
  }
  const int lo = (b == 0) ? 0 : bc[b - 1];

  arr[t] = 0; cur[t] = 0;
  __syncthreads();
  for (int i = t; i < cnt; i += 512) {
    u32 v = pairBuf[pb + i];
    atomicAdd(&arr[v >> 18], 1);
  }
  __syncthreads();
  int c0 = arr[t];
  __syncthreads();
  for (int dd = 1; dd < 512; dd <<= 1) {
    int v = (t >= dd) ? arr[t - dd] : 0;
    __syncthreads();
    arr[t] += v;
    __syncthreads();
  }
  int epre = arr[t] - c0;
  int gd = d0 + t;
  if (gd < n) {
    offs[gd] = lo + epre;
    dis[gd] = rsqrtf((float)c0 + 1.0f);
  }
  __syncthreads();
  arr[t] = epre;
  __syncthreads();
  for (int i = t; i < cnt; i += 512) {
    u32 v = pairBuf[pb + i];
    int ld = v >> 18;
    int p = lo + arr[ld] + atomicAdd(&cur[ld], 1);
    csr[p] = (int)(v & 0x3FFFFu);
  }
  if (b == 0 && t == 0) offs[n] = e;
}

// --- GEMM: tmp[r,:] = fp8( 16 * dis[r] * (h[r,:] @ W) ) via MFMA ------------
template <bool FP32IN>
__global__ __launch_bounds__(256) void k_gemm_mfma(const void* __restrict__ hin,
                                                   const u16* __restrict__ wp,
                                                   const float* __restrict__ dis,
                                                   u8* __restrict__ tmpf8, int n) {
  __shared__ float eps[64 * 132];
  const int tid = threadIdx.x;
  const int w = tid >> 6, l = tid & 63;
  const int g = l >> 4, c16 = l & 15;
  const int rowbase = blockIdx.x * 64 + w * 16;

  const short8v zero8 = {0, 0, 0, 0, 0, 0, 0, 0};
  short8v a[4];
  int ar = rowbase + c16;
  bool aok = ar < n;
#pragma unroll
  for (int kc = 0; kc < 4; ++kc) {
    if (FP32IN) {
      const float* hrow = (const float*)hin + (size_t)ar * 128;
      short8v s = zero8;
      if (aok) {
        float4 v0 = *reinterpret_cast<const float4*>(hrow + kc * 32 + g * 8);
        float4 v1 = *reinterpret_cast<const float4*>(hrow + kc * 32 + g * 8 + 4);
        s[0] = (short)f2bf(v0.x); s[1] = (short)f2bf(v0.y);
        s[2] = (short)f2bf(v0.z); s[3] = (short)f2bf(v0.w);
        s[4] = (short)f2bf(v1.x); s[5] = (short)f2bf(v1.y);
        s[6] = (short)f2bf(v1.z); s[7] = (short)f2bf(v1.w);
      }
      a[kc] = s;
    } else {
      const u16* hrow = (const u16*)hin + (size_t)ar * 128;
      a[kc] = aok ? *reinterpret_cast<const short8v*>(hrow + kc * 32 + g * 8) : zero8;
    }
  }

  f32x4 acc[8];
#pragma unroll
  for (int ct = 0; ct < 8; ++ct) acc[ct] = f32x4{0.f, 0.f, 0.f, 0.f};

#pragma unroll
  for (int ct = 0; ct < 8; ++ct) {
#pragma unroll
    for (int kc = 0; kc < 4; ++kc) {
      short8v b = *reinterpret_cast<const short8v*>(wp + ((size_t)(ct * 4 + kc) * 64 + l) * 8);
      acc[ct] = __builtin_amdgcn_mfma_f32_16x16x32_bf16(a[kc], b, acc[ct], 0, 0, 0);
    }
  }

  // scale by 16*dis[row] (x16 clears fp8 subnormal region; gather divides out)
#pragma unroll
  for (int j = 0; j < 4; ++j) {
    int rl = w * 16 + g * 4 + j;
    int gr = blockIdx.x * 64 + rl;
    float dn = (gr < n) ? dis[gr] * 16.0f : 0.f;
#pragma unroll
    for (int ct = 0; ct < 8; ++ct)
      eps[rl * 132 + ct * 16 + c16] = acc[ct][j] * dn;
  }
  __syncthreads();

  // readback: thread -> (row rl, 32-col segment), pack fp8 and store 32B
  int rl = tid >> 2, seg = tid & 3;
  int gr = blockIdx.x * 64 + rl;
  if (gr < n) {
    const float* src = &eps[rl * 132 + seg * 32];
    u32 wds[8];
#pragma unroll
    for (int q = 0; q < 4; ++q) {
      float4 v0 = *reinterpret_cast<const float4*>(src + q * 8);
      float4 v1 = *reinterpret_cast<const float4*>(src + q * 8 + 4);
      int p0 = __builtin_amdgcn_cvt_pk_fp8_f32(v0.x, v0.y, 0, false);
      p0 = __builtin_amdgcn_cvt_pk_fp8_f32(v0.z, v0.w, p0, true);
      int p1 = __builtin_amdgcn_cvt_pk_fp8_f32(v1.x, v1.y, 0, false);
      p1 = __builtin_amdgcn_cvt_pk_fp8_f32(v1.z, v1.w, p1, true);
      wds[q * 2] = (u32)p0;
      wds[q * 2 + 1] = (u32)p1;
    }
    uint4 o0; o0.x = wds[0]; o0.y = wds[1]; o0.z = wds[2]; o0.w = wds[3];
    uint4 o1; o1.x = wds[4]; o1.y = wds[5]; o1.z = wds[6]; o1.w = wds[7];
    *reinterpret_cast<uint4*>(tmpf8 + (size_t)gr * 128 + seg * 32) = o0;
    *reinterpret_cast<uint4*>(tmpf8 + (size_t)gr * 128 + seg * 32 + 16) = o1;
  }
}

// --- gather: 4 rows/VMEM instr, quarter-wave per node (R16-proven floor) ----
// POOL: last layer — accumulate relu outputs into LDS pp[128] (block-local),
// write one coalesced partial row per block, skip houtb.
template <bool POOL>
__global__ __launch_bounds__(256) void k_gather_f8(const u8* __restrict__ tmpf8,
                                                   const int* __restrict__ csr,
                                                   const int* __restrict__ offs,
                                                   const float* __restrict__ dis,
                                                   const float* __restrict__ bias,
                                                   u16* __restrict__ houtb,
                                                   float* __restrict__ partials,
                                                   int n) {
  __shared__ float pp[128];
  int node0 = (blockIdx.x * 4 + (threadIdx.x >> 6)) * 4;
  if (!POOL && node0 >= n) return;
  if (POOL) {
    if (threadIdx.x < 128) pp[threadIdx.x] = 0.f;
    __syncthreads();
  }
  int lane = threadIdx.x & 63;
  int q = lane >> 4, l16 = lane & 15;
  const uint2* tp = reinterpret_cast<const uint2*>(tmpf8) + l16;  // per-lane base

  int s_[5];
#pragma unroll
  for (int k = 0; k < 5; ++k)
    s_[k] = __builtin_amdgcn_readfirstlane(offs[min(node0 + k, n)]);
  int len01 = max(s_[1] - s_[0], s_[2] - s_[1]);
  int len23 = max(s_[3] - s_[2], s_[4] - s_[3]);
  int nbatch = (max(len01, len23) + 7) >> 3;
  int gmax = max(s_[4] - 1, 0);

  int myStart = (q == 0) ? s_[0] : (q == 1) ? s_[1] : (q == 2) ? s_[2] : s_[3];
  int myEnd   = (q == 0) ? s_[1] : (q == 1) ? s_[2] : (q == 2) ? s_[3] : s_[4];
  int myNode = min(node0 + q, n - 1);
  bool doWrite = (node0 + q) < n;

  f32x4 aL[2], aH[2];
#pragma unroll
  for (int i = 0; i < 2; ++i) { aL[i] = f32x4{0,0,0,0}; aH[i] = f32x4{0,0,0,0}; }

  // self-loop row (issued first; latency overlaps the loop)
  {
    uint2 v = tp[(u32)myNode << 4];
    f32x2 l0 = __builtin_amdgcn_cvt_pk_f32_fp8((int)v.x, false);
    f32x2 h0 = __builtin_amdgcn_cvt_pk_f32_fp8((int)v.x, true);
    f32x2 l1 = __builtin_amdgcn_cvt_pk_f32_fp8((int)v.y, false);
    f32x2 h1 = __builtin_amdgcn_cvt_pk_f32_fp8((int)v.y, true);
    aL[0] += f32x4{l0.x, l0.y, h0.x, h0.y};
    aH[0] += f32x4{l1.x, l1.y, h1.x, h1.y};
  }

  for (int b = 0; b < nbatch; ++b) {
    int eb = b * 8;
    u32 ro[8];
    float sel[8];
#pragma unroll
    for (int j = 0; j < 8; ++j) {
      int r0 = __builtin_amdgcn_readfirstlane(csr[min(s_[0] + eb + j, gmax)]);
      int r1 = __builtin_amdgcn_readfirstlane(csr[min(s_[1] + eb + j, gmax)]);
      int r2 = __builtin_amdgcn_readfirstlane(csr[min(s_[2] + eb + j, gmax)]);
      int r3 = __builtin_amdgcn_readfirstlane(csr[min(s_[3] + eb + j, gmax)]);
      int rr = (q == 0) ? r0 : (q == 1) ? r1 : (q == 2) ? r2 : r3;
      ro[j] = (u32)rr << 4;  // uint2-unit row offset (row = 16 uint2)
      sel[j] = (myStart + eb + j < myEnd) ? 1.0f : 0.0f;
    }
    uint2 v[8];
#pragma unroll
    for (int j = 0; j < 8; ++j) v[j] = tp[ro[j]];
#pragma unroll
    for (int j = 0; j < 8; ++j) {
      f32x2 l0 = __builtin_amdgcn_cvt_pk_f32_fp8((int)v[j].x, false);
      f32x2 h0 = __builtin_amdgcn_cvt_pk_f32_fp8((int)v[j].x, true);
      f32x2 l1 = __builtin_amdgcn_cvt_pk_f32_fp8((int)v[j].y, false);
      f32x2 h1 = __builtin_amdgcn_cvt_pk_f32_fp8((int)v[j].y, true);
      aL[j & 1] += f32x4{l0.x, l0.y, h0.x, h0.y} * sel[j];
      aH[j & 1] += f32x4{l1.x, l1.y, h1.x, h1.y} * sel[j];
    }
  }

  f32x4 sL = aL[0] + aL[1];
  f32x4 sH = aH[0] + aH[1];
  float dn = dis[myNode] * 0.0625f;  // /16 undoes the fp8 pre-scale
  float4 b0v = reinterpret_cast<const float4*>(bias)[l16 * 2];
  float4 b1v = reinterpret_cast<const float4*>(bias)[l16 * 2 + 1];
  float r0 = fmaf(dn, sL.x, b0v.x); r0 = r0 > 0.f ? r0 : 0.f;
  float r1 = fmaf(dn, sL.y, b0v.y); r1 = r1 > 0.f ? r1 : 0.f;
  float r2 = fmaf(dn, sL.z, b0v.z); r2 = r2 > 0.f ? r2 : 0.f;
  float r3 = fmaf(dn, sL.w, b0v.w); r3 = r3 > 0.f ? r3 : 0.f;
  float r4 = fmaf(dn, sH.x, b1v.x); r4 = r4 > 0.f ? r4 : 0.f;
  float r5 = fmaf(dn, sH.y, b1v.y); r5 = r5 > 0.f ? r5 : 0.f;
  float r6 = fmaf(dn, sH.z, b1v.z); r6 = r6 > 0.f ? r6 : 0.f;
  float r7 = fmaf(dn, sH.w, b1v.w); r7 = r7 > 0.f ? r7 : 0.f;

  if (!POOL) {
    if (doWrite) {
      uint4 o;
      o.x = (u32)f2bf(r0) | ((u32)f2bf(r1) << 16);
      o.y = (u32)f2bf(r2) | ((u32)f2bf(r3) << 16);
      o.z = (u32)f2bf(r4) | ((u32)f2bf(r5) << 16);
      o.w = (u32)f2bf(r6) | ((u32)f2bf(r7) << 16);
      reinterpret_cast<uint4*>(houtb)[(size_t)myNode * 16 + l16] = o;
    }
  } else {
    if (doWrite) {
      int c = l16 * 8;
      atomicAdd(&pp[c + 0], r0); atomicAdd(&pp[c + 1], r1);
      atomicAdd(&pp[c + 2], r2); atomicAdd(&pp[c + 3], r3);
      atomicAdd(&pp[c + 4], r4); atomicAdd(&pp[c + 5], r5);
      atomicAdd(&pp[c + 6], r6); atomicAdd(&pp[c + 7], r7);
    }
    __syncthreads();
    if (threadIdx.x < 128)
      partials[(size_t)blockIdx.x * 128 + threadIdx.x] = pp[threadIdx.x];
  }
}

// --- reduce per-block pool partials -> pooled[128] --------------------------
__global__ __launch_bounds__(128) void k_pred(const float* __restrict__ partials,
                                              float* __restrict__ pooled, int nrow) {
  int c = threadIdx.x;
  float acc = 0.f;
  for (int r = blockIdx.x; r < nrow; r += gridDim.x)
    acc += partials[(size_t)r * 128 + c];
  atomicAdd(&pooled[c], acc);
}

__global__ void k_final(const float* __restrict__ pooled, const float* __restrict__ Wfc,
                        const float* __restrict__ bfc, float* __restrict__ out,
                        float invn) {
  int j = threadIdx.x;
  if (j < 32) {
    float acc = 0.f;
    for (int k = 0; k < 128; ++k) acc = fmaf(pooled[k], Wfc[k * 32 + j], acc);
    out[j] = fmaf(acc, invn, bfc[j]);
  }
}

extern "C" void kernel_launch(void* const* d_in, const int* in_sizes, int n_in,
                              void* d_out, int out_size, void* d_ws, size_t ws_size,
                              hipStream_t stream) {
  const float* x   = (const float*)d_in[0];
  const int*   ei  = (const int*)d_in[1];
  const float* W0  = (const float*)d_in[2];
  const float* b0  = (const float*)d_in[3];
  const float* W1  = (const float*)d_in[4];
  const float* b1  = (const float*)d_in[5];
  const float* W2  = (const float*)d_in[6];
  const float* b2  = (const float*)d_in[7];
  const float* Wfc = (const float*)d_in[8];
  const float* bfc = (const float*)d_in[9];

  const int n = in_sizes[0] / 128;
  const int e = in_sizes[1] / 2;
  const int nb = (n + (1 << BKSH) - 1) >> BKSH;

  char* ws = (char*)d_ws;
  size_t off = 0;
  auto alloc = [&](size_t bytes) -> void* {
    void* p = ws + off;
    off = (off + bytes + 255) & ~(size_t)255;
    return p;
  };
  int*   mode      = (int*)alloc(sizeof(int));
  int*   bucketCur = (int*)alloc(NBMAX * 4);
  int*   offs      = (int*)alloc((size_t)(n + 1) * 4);
  float* dis       = (float*)alloc((size_t)n * 4);
  int*   csr       = (int*)alloc((size_t)e * 4);
  float* pooled    = (float*)alloc(128 * 4);
  u16*   wp        = (u16*)alloc(3 * 2048 * 8 * 2);
  u8*    tmpf8     = (u8*)alloc((size_t)n * 128);
  u16*   houtb     = (u16*)alloc((size_t)n * 128 * 2);
  int    gn        = (n + 15) / 16;
  float* partials  = (float*)alloc((size_t)gn * 128 * 4);
  u32*   pairBuf   = (u32*)houtb;  // alias: packed padded pairs (nb*CAP*4B
                                   // <= 9.7MB) consumed before gather0 writes

  k_init<<<26, 256, 0, stream>>>(ei, mode, bucketCur, pooled, W0, W1, W2, wp, e, nb);
  b_scatter<<<(e + SCH - 1) / SCH, 256, 0, stream>>>(ei, mode, bucketCur, pairBuf, e, nb);
  b_fine<<<nb, 512, 0, stream>>>(pairBuf, bucketCur, offs, dis, csr, n, e, nb);

  int gg = (n + 63) / 64;

  // layer 0 (reads fp32 x directly)
  k_gemm_mfma<true><<<gg, 256, 0, stream>>>(x, wp, dis, tmpf8, n);
  k_gather_f8<false><<<gn, 256, 0, stream>>>(tmpf8, csr, offs, dis, b0, houtb, partials, n);
  // layer 1
  k_gemm_mfma<false><<<gg, 256, 0, stream>>>(houtb, wp + 2048 * 8, dis, tmpf8, n);
  k_gather_f8<false><<<gn, 256, 0, stream>>>(tmpf8, csr, offs, dis, b1, houtb, partials, n);
  // layer 2 (gather fuses mean-pool into per-block partials; no houtb write)
  k_gemm_mfma<false><<<gg, 256, 0, stream>>>(houtb, wp + 2 * 2048 * 8, dis, tmpf8, n);
  k_gather_f8<true><<<gn, 256, 0, stream>>>(tmpf8, csr, offs, dis, b2, houtb, partials, n);

  k_pred<<<64, 128, 0, stream>>>(partials, pooled, gn);
  k_final<<<1, 32, 0, stream>>>(pooled, Wfc, bfc, (float*)d_out, 1.0f / (float)n);
}

// Round 18
// 293.725 us; speedup vs baseline: 1.0929x; 1.0929x over previous
//
#include <hip/hip_runtime.h>
#include <hip/hip_bf16.h>
#include <cstdint>

// ---------------------------------------------------------------------------
// GCN 3-layer forward, bf16 pipeline + MFMA GEMM + fp8 gather operand.
// R18: revert R17's POOL-fused gather (+37.5us: trailing __syncthreads made
//      block lifetime = max-of-16 node degrees; LDS atomic serialization;
//      lost early-return). Keep R17's proven wins: packed u32 pairBuf,
//      bucket-scan folded into b_fine, wpack folded into k_init.
//      Gather = R16's untemplated 4-rows-per-VMEM form (51us floor);
//      separate k_pool_bf (512 blocks, ~8us).
// ---------------------------------------------------------------------------

typedef unsigned short u16;
typedef unsigned int u32;
typedef unsigned char u8;
typedef __attribute__((ext_vector_type(8))) short short8v;
typedef __attribute__((ext_vector_type(4))) float f32x4;
typedef __attribute__((ext_vector_type(2))) float f32x2;

#define NBMAX 256
#define BKSH  9
#define SCH   2048
#define CAP   12288   // padded pair slots per bucket

__device__ inline u16 f2bf(float f) {
  u32 u = __float_as_uint(f);
  u += 0x7fff + ((u >> 16) & 1);  // RNE
  return (u16)(u >> 16);
}
__device__ inline float bflo(u32 u) { return __uint_as_float(u << 16); }
__device__ inline float bfhi(u32 u) { return __uint_as_float(u & 0xffff0000u); }

// --- init: blk0 detect edge dtype, blk1 zero cursors/pooled, blk2-25 wpack --
__global__ __launch_bounds__(256) void k_init(const int* __restrict__ ei,
                                              int* __restrict__ mode,
                                              int* __restrict__ bucketCur,
                                              float* __restrict__ pooled,
                                              const float* __restrict__ W0,
                                              const float* __restrict__ W1,
                                              const float* __restrict__ W2,
                                              u16* __restrict__ wp,
                                              int e, int nb) {
  int bid = blockIdx.x;
  if (bid == 0) {
    __shared__ int any;
    if (threadIdx.x == 0) any = 0;
    __syncthreads();
    int lim = min(e, 2048);
    int local = 0;
    for (int i = threadIdx.x; i < lim; i += blockDim.x)
      local |= (ei[2 * i + 1] != 0);
    if (local) atomicOr(&any, 1);
    __syncthreads();
    if (threadIdx.x == 0) mode[0] = (any == 0) ? 1 : 0;
  } else if (bid == 1) {
    int i = threadIdx.x;
    if (i < nb) bucketCur[i] = 0;
    if (i < 128) pooled[i] = 0.0f;
  } else {
    int f = (bid - 2) * 256 + threadIdx.x;   // 0..6143
    int wsel = f >> 11;
    int li = f & 2047;
    const float* W = (wsel == 0) ? W0 : (wsel == 1) ? W1 : W2;
    u16* dst = wp + (size_t)wsel * 2048 * 8;
    int ct = li >> 8, kc = (li >> 6) & 3, lane = li & 63;
    int g = lane >> 4, c = lane & 15;
    u32 o[4];
#pragma unroll
    for (int q = 0; q < 4; ++q) {
      int k = kc * 32 + g * 8 + q * 2;
      u16 e0 = f2bf(W[(size_t)k * 128 + ct * 16 + c]);
      u16 e1 = f2bf(W[(size_t)(k + 1) * 128 + ct * 16 + c]);
      o[q] = (u32)e0 | ((u32)e1 << 16);
    }
    uint4 v; v.x = o[0]; v.y = o[1]; v.z = o[2]; v.w = o[3];
    *reinterpret_cast<uint4*>(dst + (size_t)li * 8) = v;
  }
}

// --- scatter packed edges (src:18b | dstLocal:9b) into padded buckets -------
__global__ __launch_bounds__(256) void b_scatter(const int* __restrict__ ei,
                                                 const int* __restrict__ mode,
                                                 int* __restrict__ bucketCur,
                                                 u32* __restrict__ pairBuf,
                                                 int e, int nb) {
  __shared__ int cnt[NBMAX];
  __shared__ int pre[NBMAX];
  __shared__ int base[NBMAX];
  __shared__ u32 stage[SCH];
  const int t = threadIdx.x;
  const int chunk0 = blockIdx.x * SCH;
  const int nloc = min(SCH, e - chunk0);
  const int m = mode[0];

  cnt[t] = 0;
  __syncthreads();

  u32 myP[SCH / 256];
  int myB[SCH / 256], mySlot[SCH / 256];
#pragma unroll
  for (int j = 0; j < SCH / 256; ++j) {
    int li = j * 256 + t;
    myB[j] = -1;
    if (li < nloc) {
      int i = chunk0 + li;
      long long di = (long long)e + i;
      int s = m ? ei[2 * (long long)i] : ei[i];
      int d = m ? ei[2 * di] : ei[di];
      int b = d >> BKSH;
      myP[j] = (u32)s | ((u32)(d & ((1 << BKSH) - 1)) << 18);
      myB[j] = b;
      mySlot[j] = atomicAdd(&cnt[b], 1);
    }
  }
  __syncthreads();

  int c0 = cnt[t];
  pre[t] = c0;
  __syncthreads();
  for (int d = 1; d < NBMAX; d <<= 1) {
    int v = (t >= d) ? pre[t - d] : 0;
    __syncthreads();
    pre[t] += v;
    __syncthreads();
  }
  int myPre = pre[t] - c0;
  if (t < nb && c0 > 0) base[t] = atomicAdd(&bucketCur[t], c0);  // bucket-rel
  __syncthreads();
  cnt[t] = myPre;
  __syncthreads();

#pragma unroll
  for (int j = 0; j < SCH / 256; ++j) {
    if (myB[j] >= 0)
      stage[cnt[myB[j]] + mySlot[j]] = myP[j];
  }
  __syncthreads();

  int wave = t >> 6, lane = t & 63;
  for (int b = wave; b < nb; b += 4) {
    int cb = pre[b] - cnt[b];
    if (cb <= 0) continue;
    int lo = cnt[b];
    int gb = base[b];
    int room = CAP - gb;
    int allowed = (room > 0) ? min(cb, room) : 0;  // overflow guard (impossible)
    size_t dst = (size_t)b * CAP + gb;
    for (int j = lane; j < allowed; j += 64)
      pairBuf[dst + j] = stage[lo + j];
  }
}

// --- per-bucket fine CSR from packed padded pairs; own bucket-offset scan ---
__global__ __launch_bounds__(512) void b_fine(const u32* __restrict__ pairBuf,
                                              const int* __restrict__ bucketCur,
                                              int* __restrict__ offs,
                                              float* __restrict__ dis,
                                              int* __restrict__ csr,
                                              int n, int e, int nb) {
  const int b = blockIdx.x;
  const int d0 = b << BKSH;
  const size_t pb = (size_t)b * CAP;
  const int cnt = bucketCur[b];
  __shared__ int bc[NBMAX];
  __shared__ int arr[1 << BKSH];
  __shared__ int cur[1 << BKSH];
  const int t = threadIdx.x;

  // exclusive-scan all bucket counts to find this bucket's global csr base
  if (t < NBMAX) bc[t] = (t < nb) ? bucketCur[t] : 0;
  __syncthreads();
  for (int d = 1; d < NBMAX; d <<= 1) {
    int v = (t < NBMAX && t >= d) ? bc[t - d] : 0;
    __syncthreads();
    if (t < NBMAX) bc[t] += v;
    __syncthreads();
  }
  const int lo = (b == 0) ? 0 : bc[b - 1];

  arr[t] = 0; cur[t] = 0;
  __syncthreads();
  for (int i = t; i < cnt; i += 512) {
    u32 v = pairBuf[pb + i];
    atomicAdd(&arr[v >> 18], 1);
  }
  __syncthreads();
  int c0 = arr[t];
  __syncthreads();
  for (int dd = 1; dd < 512; dd <<= 1) {
    int v = (t >= dd) ? arr[t - dd] : 0;
    __syncthreads();
    arr[t] += v;
    __syncthreads();
  }
  int epre = arr[t] - c0;
  int gd = d0 + t;
  if (gd < n) {
    offs[gd] = lo + epre;
    dis[gd] = rsqrtf((float)c0 + 1.0f);
  }
  __syncthreads();
  arr[t] = epre;
  __syncthreads();
  for (int i = t; i < cnt; i += 512) {
    u32 v = pairBuf[pb + i];
    int ld = v >> 18;
    int p = lo + arr[ld] + atomicAdd(&cur[ld], 1);
    csr[p] = (int)(v & 0x3FFFFu);
  }
  if (b == 0 && t == 0) offs[n] = e;
}

// --- GEMM: tmp[r,:] = fp8( 16 * dis[r] * (h[r,:] @ W) ) via MFMA ------------
template <bool FP32IN>
__global__ __launch_bounds__(256) void k_gemm_mfma(const void* __restrict__ hin,
                                                   const u16* __restrict__ wp,
                                                   const float* __restrict__ dis,
                                                   u8* __restrict__ tmpf8, int n) {
  __shared__ float eps[64 * 132];
  const int tid = threadIdx.x;
  const int w = tid >> 6, l = tid & 63;
  const int g = l >> 4, c16 = l & 15;
  const int rowbase = blockIdx.x * 64 + w * 16;

  const short8v zero8 = {0, 0, 0, 0, 0, 0, 0, 0};
  short8v a[4];
  int ar = rowbase + c16;
  bool aok = ar < n;
#pragma unroll
  for (int kc = 0; kc < 4; ++kc) {
    if (FP32IN) {
      const float* hrow = (const float*)hin + (size_t)ar * 128;
      short8v s = zero8;
      if (aok) {
        float4 v0 = *reinterpret_cast<const float4*>(hrow + kc * 32 + g * 8);
        float4 v1 = *reinterpret_cast<const float4*>(hrow + kc * 32 + g * 8 + 4);
        s[0] = (short)f2bf(v0.x); s[1] = (short)f2bf(v0.y);
        s[2] = (short)f2bf(v0.z); s[3] = (short)f2bf(v0.w);
        s[4] = (short)f2bf(v1.x); s[5] = (short)f2bf(v1.y);
        s[6] = (short)f2bf(v1.z); s[7] = (short)f2bf(v1.w);
      }
      a[kc] = s;
    } else {
      const u16* hrow = (const u16*)hin + (size_t)ar * 128;
      a[kc] = aok ? *reinterpret_cast<const short8v*>(hrow + kc * 32 + g * 8) : zero8;
    }
  }

  f32x4 acc[8];
#pragma unroll
  for (int ct = 0; ct < 8; ++ct) acc[ct] = f32x4{0.f, 0.f, 0.f, 0.f};

#pragma unroll
  for (int ct = 0; ct < 8; ++ct) {
#pragma unroll
    for (int kc = 0; kc < 4; ++kc) {
      short8v b = *reinterpret_cast<const short8v*>(wp + ((size_t)(ct * 4 + kc) * 64 + l) * 8);
      acc[ct] = __builtin_amdgcn_mfma_f32_16x16x32_bf16(a[kc], b, acc[ct], 0, 0, 0);
    }
  }

  // scale by 16*dis[row] (x16 clears fp8 subnormal region; gather divides out)
#pragma unroll
  for (int j = 0; j < 4; ++j) {
    int rl = w * 16 + g * 4 + j;
    int gr = blockIdx.x * 64 + rl;
    float dn = (gr < n) ? dis[gr] * 16.0f : 0.f;
#pragma unroll
    for (int ct = 0; ct < 8; ++ct)
      eps[rl * 132 + ct * 16 + c16] = acc[ct][j] * dn;
  }
  __syncthreads();

  // readback: thread -> (row rl, 32-col segment), pack fp8 and store 32B
  int rl = tid >> 2, seg = tid & 3;
  int gr = blockIdx.x * 64 + rl;
  if (gr < n) {
    const float* src = &eps[rl * 132 + seg * 32];
    u32 wds[8];
#pragma unroll
    for (int q = 0; q < 4; ++q) {
      float4 v0 = *reinterpret_cast<const float4*>(src + q * 8);
      float4 v1 = *reinterpret_cast<const float4*>(src + q * 8 + 4);
      int p0 = __builtin_amdgcn_cvt_pk_fp8_f32(v0.x, v0.y, 0, false);
      p0 = __builtin_amdgcn_cvt_pk_fp8_f32(v0.z, v0.w, p0, true);
      int p1 = __builtin_amdgcn_cvt_pk_fp8_f32(v1.x, v1.y, 0, false);
      p1 = __builtin_amdgcn_cvt_pk_fp8_f32(v1.z, v1.w, p1, true);
      wds[q * 2] = (u32)p0;
      wds[q * 2 + 1] = (u32)p1;
    }
    uint4 o0; o0.x = wds[0]; o0.y = wds[1]; o0.z = wds[2]; o0.w = wds[3];
    uint4 o1; o1.x = wds[4]; o1.y = wds[5]; o1.z = wds[6]; o1.w = wds[7];
    *reinterpret_cast<uint4*>(tmpf8 + (size_t)gr * 128 + seg * 32) = o0;
    *reinterpret_cast<uint4*>(tmpf8 + (size_t)gr * 128 + seg * 32 + 16) = o1;
  }
}

// --- gather: 4 rows/VMEM instr, quarter-wave per node (R16-proven floor) ----
__global__ __launch_bounds__(256) void k_gather_f8(const u8* __restrict__ tmpf8,
                                                   const int* __restrict__ csr,
                                                   const int* __restrict__ offs,
                                                   const float* __restrict__ dis,
                                                   const float* __restrict__ bias,
                                                   u16* __restrict__ houtb, int n) {
  int node0 = (blockIdx.x * 4 + (threadIdx.x >> 6)) * 4;
  if (node0 >= n) return;
  int lane = threadIdx.x & 63;
  int q = lane >> 4, l16 = lane & 15;
  const uint2* tp = reinterpret_cast<const uint2*>(tmpf8) + l16;  // per-lane base

  int s_[5];
#pragma unroll
  for (int k = 0; k < 5; ++k)
    s_[k] = __builtin_amdgcn_readfirstlane(offs[min(node0 + k, n)]);
  int len01 = max(s_[1] - s_[0], s_[2] - s_[1]);
  int len23 = max(s_[3] - s_[2], s_[4] - s_[3]);
  int nbatch = (max(len01, len23) + 7) >> 3;
  int gmax = max(s_[4] - 1, 0);

  int myStart = (q == 0) ? s_[0] : (q == 1) ? s_[1] : (q == 2) ? s_[2] : s_[3];
  int myEnd   = (q == 0) ? s_[1] : (q == 1) ? s_[2] : (q == 2) ? s_[3] : s_[4];
  int myNode = min(node0 + q, n - 1);
  bool doWrite = (node0 + q) < n;

  f32x4 aL[2], aH[2];
#pragma unroll
  for (int i = 0; i < 2; ++i) { aL[i] = f32x4{0,0,0,0}; aH[i] = f32x4{0,0,0,0}; }

  // self-loop row (issued first; latency overlaps the loop)
  {
    uint2 v = tp[(u32)myNode << 4];
    f32x2 l0 = __builtin_amdgcn_cvt_pk_f32_fp8((int)v.x, false);
    f32x2 h0 = __builtin_amdgcn_cvt_pk_f32_fp8((int)v.x, true);
    f32x2 l1 = __builtin_amdgcn_cvt_pk_f32_fp8((int)v.y, false);
    f32x2 h1 = __builtin_amdgcn_cvt_pk_f32_fp8((int)v.y, true);
    aL[0] += f32x4{l0.x, l0.y, h0.x, h0.y};
    aH[0] += f32x4{l1.x, l1.y, h1.x, h1.y};
  }

  for (int b = 0; b < nbatch; ++b) {
    int eb = b * 8;
    u32 ro[8];
    float sel[8];
#pragma unroll
    for (int j = 0; j < 8; ++j) {
      int r0 = __builtin_amdgcn_readfirstlane(csr[min(s_[0] + eb + j, gmax)]);
      int r1 = __builtin_amdgcn_readfirstlane(csr[min(s_[1] + eb + j, gmax)]);
      int r2 = __builtin_amdgcn_readfirstlane(csr[min(s_[2] + eb + j, gmax)]);
      int r3 = __builtin_amdgcn_readfirstlane(csr[min(s_[3] + eb + j, gmax)]);
      int rr = (q == 0) ? r0 : (q == 1) ? r1 : (q == 2) ? r2 : r3;
      ro[j] = (u32)rr << 4;  // uint2-unit row offset (row = 16 uint2)
      sel[j] = (myStart + eb + j < myEnd) ? 1.0f : 0.0f;
    }
    uint2 v[8];
#pragma unroll
    for (int j = 0; j < 8; ++j) v[j] = tp[ro[j]];
#pragma unroll
    for (int j = 0; j < 8; ++j) {
      f32x2 l0 = __builtin_amdgcn_cvt_pk_f32_fp8((int)v[j].x, false);
      f32x2 h0 = __builtin_amdgcn_cvt_pk_f32_fp8((int)v[j].x, true);
      f32x2 l1 = __builtin_amdgcn_cvt_pk_f32_fp8((int)v[j].y, false);
      f32x2 h1 = __builtin_amdgcn_cvt_pk_f32_fp8((int)v[j].y, true);
      aL[j & 1] += f32x4{l0.x, l0.y, h0.x, h0.y} * sel[j];
      aH[j & 1] += f32x4{l1.x, l1.y, h1.x, h1.y} * sel[j];
    }
  }

  f32x4 sL = aL[0] + aL[1];
  f32x4 sH = aH[0] + aH[1];
  float dn = dis[myNode] * 0.0625f;  // /16 undoes the fp8 pre-scale
  float4 b0v = reinterpret_cast<const float4*>(bias)[l16 * 2];
  float4 b1v = reinterpret_cast<const float4*>(bias)[l16 * 2 + 1];
  float r0 = fmaf(dn, sL.x, b0v.x); r0 = r0 > 0.f ? r0 : 0.f;
  float r1 = fmaf(dn, sL.y, b0v.y); r1 = r1 > 0.f ? r1 : 0.f;
  float r2 = fmaf(dn, sL.z, b0v.z); r2 = r2 > 0.f ? r2 : 0.f;
  float r3 = fmaf(dn, sL.w, b0v.w); r3 = r3 > 0.f ? r3 : 0.f;
  float r4 = fmaf(dn, sH.x, b1v.x); r4 = r4 > 0.f ? r4 : 0.f;
  float r5 = fmaf(dn, sH.y, b1v.y); r5 = r5 > 0.f ? r5 : 0.f;
  float r6 = fmaf(dn, sH.z, b1v.z); r6 = r6 > 0.f ? r6 : 0.f;
  float r7 = fmaf(dn, sH.w, b1v.w); r7 = r7 > 0.f ? r7 : 0.f;
  if (doWrite) {
    uint4 o;
    o.x = (u32)f2bf(r0) | ((u32)f2bf(r1) << 16);
    o.y = (u32)f2bf(r2) | ((u32)f2bf(r3) << 16);
    o.z = (u32)f2bf(r4) | ((u32)f2bf(r5) << 16);
    o.w = (u32)f2bf(r6) | ((u32)f2bf(r7) << 16);
    reinterpret_cast<uint4*>(houtb)[(size_t)myNode * 16 + l16] = o;
  }
}

// --- mean-pool column sums (bf16 in, fp32 out); 512 blocks -> 65K atomics ---
__global__ __launch_bounds__(256) void k_pool_bf(const u16* __restrict__ h,
                                                 float* __restrict__ pooled, int n) {
  int lane = threadIdx.x & 63, wv = threadIdx.x >> 6;
  const u32* hp = reinterpret_cast<const u32*>(h);
  float sx = 0.f, sy = 0.f;
  for (int r = blockIdx.x * 4 + wv; r < n; r += gridDim.x * 4) {
    u32 u = hp[(size_t)r * 64 + lane];
    sx += bflo(u); sy += bfhi(u);
  }
  __shared__ float red[2][256];
  red[0][threadIdx.x] = sx;
  red[1][threadIdx.x] = sy;
  __syncthreads();
  if (threadIdx.x < 64) {
    float tx = red[0][threadIdx.x] + red[0][threadIdx.x + 64] +
               red[0][threadIdx.x + 128] + red[0][threadIdx.x + 192];
    float ty = red[1][threadIdx.x] + red[1][threadIdx.x + 64] +
               red[1][threadIdx.x + 128] + red[1][threadIdx.x + 192];
    atomicAdd(&pooled[threadIdx.x * 2], tx);
    atomicAdd(&pooled[threadIdx.x * 2 + 1], ty);
  }
}

__global__ void k_final(const float* __restrict__ pooled, const float* __restrict__ Wfc,
                        const float* __restrict__ bfc, float* __restrict__ out,
                        float invn) {
  int j = threadIdx.x;
  if (j < 32) {
    float acc = 0.f;
    for (int k = 0; k < 128; ++k) acc = fmaf(pooled[k], Wfc[k * 32 + j], acc);
    out[j] = fmaf(acc, invn, bfc[j]);
  }
}

extern "C" void kernel_launch(void* const* d_in, const int* in_sizes, int n_in,
                              void* d_out, int out_size, void* d_ws, size_t ws_size,
                              hipStream_t stream) {
  const float* x   = (const float*)d_in[0];
  const int*   ei  = (const int*)d_in[1];
  const float* W0  = (const float*)d_in[2];
  const float* b0  = (const float*)d_in[3];
  const float* W1  = (const float*)d_in[4];
  const float* b1  = (const float*)d_in[5];
  const float* W2  = (const float*)d_in[6];
  const float* b2  = (const float*)d_in[7];
  const float* Wfc = (const float*)d_in[8];
  const float* bfc = (const float*)d_in[9];

  const int n = in_sizes[0] / 128;
  const int e = in_sizes[1] / 2;
  const int nb = (n + (1 << BKSH) - 1) >> BKSH;

  char* ws = (char*)d_ws;
  size_t off = 0;
  auto alloc = [&](size_t bytes) -> void* {
    void* p = ws + off;
    off = (off + bytes + 255) & ~(size_t)255;
    return p;
  };
  int*   mode      = (int*)alloc(sizeof(int));
  int*   bucketCur = (int*)alloc(NBMAX * 4);
  int*   offs      = (int*)alloc((size_t)(n + 1) * 4);
  float* dis       = (float*)alloc((size_t)n * 4);
  int*   csr       = (int*)alloc((size_t)e * 4);
  float* pooled    = (float*)alloc(128 * 4);
  u16*   wp        = (u16*)alloc(3 * 2048 * 8 * 2);
  u8*    tmpf8     = (u8*)alloc((size_t)n * 128);
  u16*   houtb     = (u16*)alloc((size_t)n * 128 * 2);
  u32*   pairBuf   = (u32*)houtb;  // alias: packed padded pairs (nb*CAP*4B
                                   // <= 9.7MB) consumed before gather0 writes

  k_init<<<26, 256, 0, stream>>>(ei, mode, bucketCur, pooled, W0, W1, W2, wp, e, nb);
  b_scatter<<<(e + SCH - 1) / SCH, 256, 0, stream>>>(ei, mode, bucketCur, pairBuf, e, nb);
  b_fine<<<nb, 512, 0, stream>>>(pairBuf, bucketCur, offs, dis, csr, n, e, nb);

  int gg = (n + 63) / 64;
  int gn = (n + 15) / 16;

  // layer 0 (reads fp32 x directly)
  k_gemm_mfma<true><<<gg, 256, 0, stream>>>(x, wp, dis, tmpf8, n);
  k_gather_f8<<<gn, 256, 0, stream>>>(tmpf8, csr, offs, dis, b0, houtb, n);
  // layer 1
  k_gemm_mfma<false><<<gg, 256, 0, stream>>>(houtb, wp + 2048 * 8, dis, tmpf8, n);
  k_gather_f8<<<gn, 256, 0, stream>>>(tmpf8, csr, offs, dis, b1, houtb, n);
  // layer 2
  k_gemm_mfma<false><<<gg, 256, 0, stream>>>(houtb, wp + 2 * 2048 * 8, dis, tmpf8, n);
  k_gather_f8<<<gn, 256, 0, stream>>>(tmpf8, csr, offs, dis, b2, houtb, n);

  k_pool_bf<<<512, 256, 0, stream>>>(houtb, pooled, n);
  k_final<<<1, 32, 0, stream>>>(pooled, Wfc, bfc, (float*)d_out, 1.0f / (float)n);
}